// Round 2
// baseline (147.048 us; speedup 1.0000x reference)
//
#include <hip/hip_runtime.h>
#include <math.h>

// Problem constants (B,S,D,P,M from the reference)
#define BB 4
#define SS 8192
#define DD 512
#define PP 32
#define TT (PP + SS)            // 8224 tokens after concat
#define EPSV 1e-5f

// Native vector type for nontemporal builtins (HIP_vector_type<float,4> is a
// struct, which __builtin_nontemporal_* rejects; ext_vector_type works).
typedef float vfloat4 __attribute__((ext_vector_type(4)));

// Algebraic collapse (round 1): state0=0 => write-attn uniform => state rows
// identical => read-attn uniform => mem_out[b,t,:] = vbar[b,:] = cbar@Wv+bv
// where cbar = mean over T of concat(pm,x). Output = (LN(vbar)*g+b)@Wout+bout
// broadcast over all t. Wk/bk/Wq/bq are mathematically dead.
//
// Round 3 lesson: atomic-counter grid barrier costs ~77us/barrier on MI355X
// (cross-XCD invalidation storm). Kernel-boundary sync (~3us) is cheaper.
//
// This round (polish): nontemporal loads on the x stream, nontemporal stores
// on the out stream, div-free bcast addressing with z cached in registers.
// Mandatory traffic floor = 134.5 MB @ 6.6 TB/s = 20.4 us; the remainder of
// the measured window is harness re-poison fills (257 MiB @ ~41 us each).
//
// ws layout (floats), all plain-store partials (no memset needed):
//   part [1024*DD]  colsum partials, 2 MB
//   vpart[128*DD]   split-K partials of cbar@Wv, 256 KB
//   z    [BB*DD]    final projection accum (zero-init by k_vbar, atomicAdd by k_zmat)

// ---------------------------------------------------------------------------
// Stage 1: part[blk, :] = column-sum of a 32-row chunk of x.
// 1024 blocks x 512 threads = 8192 waves = full 32-waves/CU oversubscription.
// 8 independent nontemporal float4 loads in flight per thread.
// ---------------------------------------------------------------------------
__global__ __launch_bounds__(512) void k_colsum(const vfloat4* __restrict__ x4,
                                                float4* __restrict__ part4) {
  const int bb    = blockIdx.x >> 8;    // batch (256 chunks per batch)
  const int chunk = blockIdx.x & 255;   // 32-row chunk
  const int tid   = threadIdx.x;

  const vfloat4* p = x4 + ((size_t)bb * SS + (size_t)chunk * 32) * (DD / 4);

  float ax = 0.f, ay = 0.f, az = 0.f, aw = 0.f;
#pragma unroll
  for (int i = 0; i < 8; ++i) {         // 8*512 float4 = 32 rows
    vfloat4 t = __builtin_nontemporal_load(p + i * 512 + tid);
    ax += t.x; ay += t.y; az += t.z; aw += t.w;
  }

  __shared__ float4 sh[512];
  sh[tid] = make_float4(ax, ay, az, aw);
  __syncthreads();

  // threads tid, tid+128, tid+256, tid+384 share column-group tid&127
  if (tid < 128) {
    float4 a0 = sh[tid], a1 = sh[tid + 128], a2 = sh[tid + 256], a3 = sh[tid + 384];
    part4[blockIdx.x * 128 + tid] =
        make_float4(a0.x + a1.x + a2.x + a3.x, a0.y + a1.y + a2.y + a3.y,
                    a0.z + a1.z + a2.z + a3.z, a0.w + a1.w + a2.w + a3.w);
  }
}

// ---------------------------------------------------------------------------
// Stage 2: vpart[bb,ch,j] = cbar[16-chunk] @ Wv[16-chunk, j], plain store.
// Grid: BB*32 = 128 blocks, 512 threads. cbar chunk computed by reducing the
// 256 colsum partials of this batch + the 32 persistent-memory rows.
// Blocks 0..3 also zero-init z for stage 3's atomicAdd.
// ---------------------------------------------------------------------------
__global__ __launch_bounds__(512) void k_vbar(const float* __restrict__ part,
                                              const float* __restrict__ pm,
                                              const float* __restrict__ Wv,
                                              float* __restrict__ vpart,
                                              float* __restrict__ z) {
  const int bb = blockIdx.x >> 5;       // batch
  const int ch = blockIdx.x & 31;       // 16-column chunk of cbar
  const int j  = threadIdx.x;

  __shared__ float aSh[16];
  {
    const int d16  = j >> 5;            // 16 groups of 32 lanes
    const int lane = j & 31;
    const int col  = ch * 16 + d16;
    float s = 0.f;
#pragma unroll
    for (int k = 0; k < 8; ++k)         // 256 partial rows of this batch
      s += part[(size_t)(bb * 256 + lane + 32 * k) * DD + col];
    s += pm[lane * DD + col];           // 32 persistent tokens, one per lane
#pragma unroll
    for (int off = 16; off > 0; off >>= 1) s += __shfl_down(s, off, 32);
    if (lane == 0) aSh[d16] = s * (1.0f / (float)TT);
  }
  __syncthreads();

  float acc = 0.f;
#pragma unroll
  for (int i = 0; i < 16; ++i)
    acc += aSh[i] * Wv[(ch * 16 + i) * DD + j];
  vpart[(bb * 32 + ch) * DD + j] = acc;

  if (blockIdx.x < BB) z[blockIdx.x * DD + j] = 0.f;   // init for stage 3
}

// ---------------------------------------------------------------------------
// Stage 3: vbar = bv + sum of vpart chunks; LN stats (redundant per block);
// z[b,j] += y[16-chunk] @ Wout[16-chunk, j]. Grid: 128 blocks, 512 threads.
// ---------------------------------------------------------------------------
__global__ __launch_bounds__(512) void k_zmat(const float* __restrict__ vpart,
                                              const float* __restrict__ bv,
                                              const float* __restrict__ gamma,
                                              const float* __restrict__ beta,
                                              const float* __restrict__ Wout,
                                              float* __restrict__ z) {
  const int bb = blockIdx.x >> 5;
  const int ch = blockIdx.x & 31;
  const int j  = threadIdx.x;

  float v = bv[j];
#pragma unroll
  for (int c = 0; c < 32; ++c) v += vpart[(bb * 32 + c) * DD + j];

  // block mean/var across 512 threads
  float v1 = v, v2 = v * v;
#pragma unroll
  for (int off = 32; off > 0; off >>= 1) {
    v1 += __shfl_down(v1, off, 64);
    v2 += __shfl_down(v2, off, 64);
  }
  __shared__ float w1[8], w2[8];
  const int wave = j >> 6;
  if ((j & 63) == 0) { w1[wave] = v1; w2[wave] = v2; }
  __syncthreads();
  float t1 = 0.f, t2 = 0.f;
#pragma unroll
  for (int w = 0; w < 8; ++w) { t1 += w1[w]; t2 += w2[w]; }
  const float mu  = t1 * (1.0f / (float)DD);
  const float var = t2 * (1.0f / (float)DD) - mu * mu;
  const float inv = 1.0f / sqrtf(var + EPSV);

  __shared__ float y[DD];
  y[j] = (v - mu) * inv * gamma[j] + beta[j];
  __syncthreads();

  float acc = 0.f;
#pragma unroll
  for (int i = 0; i < 16; ++i)
    acc += y[ch * 16 + i] * Wout[(ch * 16 + i) * DD + j];
  atomicAdd(&z[bb * DD + j], acc);
}

// ---------------------------------------------------------------------------
// Stage 4: out[b,t,:] = z[b,:] + bout, broadcast over all t.
// Grid: dim3(1028, BB) x 256 threads; each thread loads z/bout ONCE
// (column group tid&127 is invariant: 256 and 1024 are multiples of 128)
// and issues 4 nontemporal float4 stores. No integer division.
// 1028 * 1024 float4 = 1,052,672 = T*D/4 per batch, exact, no tail.
// ---------------------------------------------------------------------------
__global__ __launch_bounds__(256) void k_bcast(const float4* __restrict__ z4,
                                               const float4* __restrict__ bout4,
                                               vfloat4* __restrict__ out4) {
  const int bb  = blockIdx.y;
  const int tid = threadIdx.x;
  const int j4  = tid & 127;            // column group (D/4 = 128)

  float4 zz = z4[bb * 128 + j4];
  float4 bo = bout4[j4];
  vfloat4 val;
  val.x = zz.x + bo.x; val.y = zz.y + bo.y;
  val.z = zz.z + bo.z; val.w = zz.w + bo.w;

  vfloat4* o = out4 + (size_t)bb * 1052672u + (size_t)blockIdx.x * 1024u + tid;
#pragma unroll
  for (int k = 0; k < 4; ++k)
    __builtin_nontemporal_store(val, o + k * 256);
}

// ---------------------------------------------------------------------------
extern "C" void kernel_launch(void* const* d_in, const int* in_sizes, int n_in,
                              void* d_out, int out_size, void* d_ws, size_t ws_size,
                              hipStream_t stream) {
  // setup_inputs() order:
  // 0:x 1:persistent_memory 2:Wk 3:bk 4:Wv 5:bv 6:Wq 7:bq 8:gamma 9:beta
  // 10:Wout 11:bout      (Wk/bk/Wq/bq mathematically dead — see round 1)
  const float* x     = (const float*)d_in[0];
  const float* pm    = (const float*)d_in[1];
  const float* Wv    = (const float*)d_in[4];
  const float* bv    = (const float*)d_in[5];
  const float* gamma = (const float*)d_in[8];
  const float* beta  = (const float*)d_in[9];
  const float* Wout  = (const float*)d_in[10];
  const float* bout  = (const float*)d_in[11];

  float* part  = (float*)d_ws;            // 1024*DD floats (2 MB)
  float* vpart = part + 1024 * DD;        // 128*DD floats (256 KB)
  float* z     = vpart + 128 * DD;        // BB*DD floats (8 KB)

  k_colsum<<<1024, 512, 0, stream>>>((const vfloat4*)x, (float4*)part);

  k_vbar<<<BB * 32, 512, 0, stream>>>(part, pm, Wv, vpart, z);

  k_zmat<<<BB * 32, 512, 0, stream>>>(vpart, bv, gamma, beta, Wout, z);

  k_bcast<<<dim3(1028, BB), 256, 0, stream>>>((const float4*)z,
                                              (const float4*)bout,
                                              (vfloat4*)d_out);
}

// Round 4
// 141.124 us; speedup vs baseline: 1.0420x; 1.0420x over previous
//
#include <hip/hip_runtime.h>
#include <math.h>

// Problem constants (B,S,D,P,M from the reference)
#define BB 4
#define SS 8192
#define DD 512
#define PP 32
#define TT (PP + SS)            // 8224 tokens after concat
#define EPSV 1e-5f

// Algebraic collapse (round 1): state0=0 => write-attn uniform => state rows
// identical => read-attn uniform => mem_out[b,t,:] = vbar[b,:] = cbar@Wv+bv
// where cbar = mean over T of concat(pm,x). Output = (LN(vbar)*g+b)@Wout+bout
// broadcast over all t. Wk/bk/Wq/bq are mathematically dead.
//
// Round 3 lesson (prev session): atomic-counter grid barrier costs ~77us per
// barrier on MI355X (cross-XCD invalidation storm). Kernel-boundary sync
// (~3us) is cheaper. 4 launches are forced by two full-width reductions:
// cbar needs all token rows; LN needs all D columns of vbar.
//
// nt lesson (this session, round 2): __builtin_nontemporal_load/store on the
// x/out streams REGRESSED our slice ~20% (142.6 -> 147.0 us). x and out both
// fit in the 256 MiB L3; across timed iterations plain loads/stores are
// L3-serviced, and the nt flag defeats that retention. Keep plain accesses.
//
// ws layout (floats), all plain-store partials (no memset needed):
//   part [1024*DD]  colsum partials, 2 MB
//   vpart[128*DD]   split-K partials of cbar@Wv, 256 KB
//   z    [BB*DD]    final projection accum (zero-init by k_vbar, atomicAdd by k_zmat)

// ---------------------------------------------------------------------------
// Stage 1: part[blk, :] = column-sum of a 32-row chunk of x.
// 1024 blocks x 512 threads = 8192 waves = full 32-waves/CU oversubscription.
// 8 independent float4 loads in flight per thread.
// ---------------------------------------------------------------------------
__global__ __launch_bounds__(512) void k_colsum(const float4* __restrict__ x4,
                                                float4* __restrict__ part4) {
  const int bb    = blockIdx.x >> 8;    // batch (256 chunks per batch)
  const int chunk = blockIdx.x & 255;   // 32-row chunk
  const int tid   = threadIdx.x;

  const float4* p = x4 + ((size_t)bb * SS + (size_t)chunk * 32) * (DD / 4);

  float ax = 0.f, ay = 0.f, az = 0.f, aw = 0.f;
#pragma unroll
  for (int i = 0; i < 8; ++i) {         // 8*512 float4 = 32 rows
    float4 t = p[i * 512 + tid];
    ax += t.x; ay += t.y; az += t.z; aw += t.w;
  }

  __shared__ float4 sh[512];
  sh[tid] = make_float4(ax, ay, az, aw);
  __syncthreads();

  // threads tid, tid+128, tid+256, tid+384 share column-group tid&127
  if (tid < 128) {
    float4 a0 = sh[tid], a1 = sh[tid + 128], a2 = sh[tid + 256], a3 = sh[tid + 384];
    part4[blockIdx.x * 128 + tid] =
        make_float4(a0.x + a1.x + a2.x + a3.x, a0.y + a1.y + a2.y + a3.y,
                    a0.z + a1.z + a2.z + a3.z, a0.w + a1.w + a2.w + a3.w);
  }
}

// ---------------------------------------------------------------------------
// Stage 2: vpart[bb,ch,j] = cbar[16-chunk] @ Wv[16-chunk, j], plain store.
// Grid: BB*32 = 128 blocks, 512 threads. cbar chunk computed by reducing the
// 256 colsum partials of this batch + the 32 persistent-memory rows.
// Blocks 0..3 also zero-init z for stage 3's atomicAdd.
// ---------------------------------------------------------------------------
__global__ __launch_bounds__(512) void k_vbar(const float* __restrict__ part,
                                              const float* __restrict__ pm,
                                              const float* __restrict__ Wv,
                                              float* __restrict__ vpart,
                                              float* __restrict__ z) {
  const int bb = blockIdx.x >> 5;       // batch
  const int ch = blockIdx.x & 31;       // 16-column chunk of cbar
  const int j  = threadIdx.x;

  __shared__ float aSh[16];
  {
    const int d16  = j >> 5;            // 16 groups of 32 lanes
    const int lane = j & 31;
    const int col  = ch * 16 + d16;
    float s = 0.f;
#pragma unroll
    for (int k = 0; k < 8; ++k)         // 256 partial rows of this batch
      s += part[(size_t)(bb * 256 + lane + 32 * k) * DD + col];
    s += pm[lane * DD + col];           // 32 persistent tokens, one per lane
#pragma unroll
    for (int off = 16; off > 0; off >>= 1) s += __shfl_down(s, off, 32);
    if (lane == 0) aSh[d16] = s * (1.0f / (float)TT);
  }
  __syncthreads();

  float acc = 0.f;
#pragma unroll
  for (int i = 0; i < 16; ++i)
    acc += aSh[i] * Wv[(ch * 16 + i) * DD + j];
  vpart[(bb * 32 + ch) * DD + j] = acc;

  if (blockIdx.x < BB) z[blockIdx.x * DD + j] = 0.f;   // init for stage 3
}

// ---------------------------------------------------------------------------
// Stage 3: vbar = bv + sum of vpart chunks; LN stats (redundant per block);
// z[b,j] += y[16-chunk] @ Wout[16-chunk, j]. Grid: 128 blocks, 512 threads.
// ---------------------------------------------------------------------------
__global__ __launch_bounds__(512) void k_zmat(const float* __restrict__ vpart,
                                              const float* __restrict__ bv,
                                              const float* __restrict__ gamma,
                                              const float* __restrict__ beta,
                                              const float* __restrict__ Wout,
                                              float* __restrict__ z) {
  const int bb = blockIdx.x >> 5;
  const int ch = blockIdx.x & 31;
  const int j  = threadIdx.x;

  float v = bv[j];
#pragma unroll
  for (int c = 0; c < 32; ++c) v += vpart[(bb * 32 + c) * DD + j];

  // block mean/var across 512 threads
  float v1 = v, v2 = v * v;
#pragma unroll
  for (int off = 32; off > 0; off >>= 1) {
    v1 += __shfl_down(v1, off, 64);
    v2 += __shfl_down(v2, off, 64);
  }
  __shared__ float w1[8], w2[8];
  const int wave = j >> 6;
  if ((j & 63) == 0) { w1[wave] = v1; w2[wave] = v2; }
  __syncthreads();
  float t1 = 0.f, t2 = 0.f;
#pragma unroll
  for (int w = 0; w < 8; ++w) { t1 += w1[w]; t2 += w2[w]; }
  const float mu  = t1 * (1.0f / (float)DD);
  const float var = t2 * (1.0f / (float)DD) - mu * mu;
  const float inv = 1.0f / sqrtf(var + EPSV);

  __shared__ float y[DD];
  y[j] = (v - mu) * inv * gamma[j] + beta[j];
  __syncthreads();

  float acc = 0.f;
#pragma unroll
  for (int i = 0; i < 16; ++i)
    acc += y[ch * 16 + i] * Wout[(ch * 16 + i) * DD + j];
  atomicAdd(&z[bb * DD + j], acc);
}

// ---------------------------------------------------------------------------
// Stage 4: out[b,t,:] = z[b,:] + bout, broadcast over all t. float4 stores.
// ---------------------------------------------------------------------------
__global__ __launch_bounds__(256) void k_bcast(const float4* __restrict__ z4,
                                               const float4* __restrict__ bout4,
                                               float4* __restrict__ out4) {
  const unsigned i  = blockIdx.x * 256u + threadIdx.x;     // float4 index
  const unsigned bb = i / 1052672u;                        // T*D/4 per batch
  const unsigned j4 = i & 127u;                            // column group (D/4=128)
  float4 zz = z4[bb * 128u + j4];
  float4 bo = bout4[j4];
  out4[i] = make_float4(zz.x + bo.x, zz.y + bo.y, zz.z + bo.z, zz.w + bo.w);
}

// ---------------------------------------------------------------------------
extern "C" void kernel_launch(void* const* d_in, const int* in_sizes, int n_in,
                              void* d_out, int out_size, void* d_ws, size_t ws_size,
                              hipStream_t stream) {
  // setup_inputs() order:
  // 0:x 1:persistent_memory 2:Wk 3:bk 4:Wv 5:bv 6:Wq 7:bq 8:gamma 9:beta
  // 10:Wout 11:bout      (Wk/bk/Wq/bq mathematically dead — see round 1)
  const float* x     = (const float*)d_in[0];
  const float* pm    = (const float*)d_in[1];
  const float* Wv    = (const float*)d_in[4];
  const float* bv    = (const float*)d_in[5];
  const float* gamma = (const float*)d_in[8];
  const float* beta  = (const float*)d_in[9];
  const float* Wout  = (const float*)d_in[10];
  const float* bout  = (const float*)d_in[11];

  float* part  = (float*)d_ws;            // 1024*DD floats (2 MB)
  float* vpart = part + 1024 * DD;        // 128*DD floats (256 KB)
  float* z     = vpart + 128 * DD;        // BB*DD floats (8 KB)

  k_colsum<<<1024, 512, 0, stream>>>((const float4*)x, (float4*)part);

  k_vbar<<<BB * 32, 512, 0, stream>>>(part, pm, Wv, vpart, z);

  k_zmat<<<BB * 32, 512, 0, stream>>>(vpart, bv, gamma, beta, Wout, z);

  const unsigned total4 = (unsigned)BB * TT * DD / 4;      // 4,210,688
  k_bcast<<<total4 / 256, 256, 0, stream>>>((const float4*)z,
                                            (const float4*)bout,
                                            (float4*)d_out);
}